// Round 12
// baseline (266.541 us; speedup 1.0000x reference)
//
#include <hip/hip_runtime.h>
#include <math.h>

#define NN 50000
#define NE 800000
#define HD 128
#define NL 3
#define NG 64
#define BN_EPS 1e-5f
#define NB 196   // dst buckets of 256 nodes
#define EPB 4096 // edges per block in bucket scatter
#define NCNT ((NE + EPB - 1) / EPB)     // 196 scatter blocks
#define CAP 8192 // fixed bucket capacity (mean 4096 + 64 sigma)
#define NREP 32  // stats replicas (TCC same-address contention /32)
#define GATHB ((NN * 16) / 256)         // 3125 cvt blocks (exact)
#define FUSEB (NN / 16)                 // 3125 fused tiles (NN = 16*3125 exactly)

typedef _Float16 f16;
typedef __attribute__((ext_vector_type(8))) _Float16 f16x8;
typedef __attribute__((ext_vector_type(4))) float f32x4;

// BN affine from replicated raw sums
__device__ __forceinline__ void bn_affine(const float* __restrict__ sR, int c,
                                          const float* __restrict__ gam,
                                          const float* __restrict__ bet,
                                          float* sc, float* sh) {
    float s0 = 0.f, s1 = 0.f;
#pragma unroll 8
    for (int r = 0; r < NREP; ++r) {
        s0 += sR[r * 256 + c];
        s1 += sR[r * 256 + 128 + c];
    }
    float invN = 1.0f / (float)NN;
    float mu = s0 * invN;
    float var = s1 * invN - mu * mu;
    var = var < 0.f ? 0.f : var;
    float s = rsqrtf(var + BN_EPS) * gam[c];
    *sc = s;
    *sh = bet[c] - mu * s;
}

// weight prep body: BN-folded Wh (fp16) + folded bias2. One block per output ch j.
__device__ __forceinline__ void wprep_body(int j, int k, float* red,
                                           const float* __restrict__ statsPrev,
                                           const float* __restrict__ gamP,
                                           const float* __restrict__ betP,
                                           const float* __restrict__ Wl,
                                           const float* __restrict__ Wr,
                                           const float* __restrict__ bl,
                                           f16* __restrict__ Wh,
                                           float* __restrict__ bias2) {
    float scp = 1.0f, shp = 0.0f;
    if (statsPrev) bn_affine(statsPrev, k & 127, gamP, betP, &scp, &shp);
    float w = (k < HD) ? Wl[j * HD + k] : Wr[j * HD + (k - HD)];
    Wh[j * 256 + k] = (f16)(w * scp);
    red[k] = shp * w;
    __syncthreads();
    for (int s = 128; s > 0; s >>= 1) {
        if (k < s) red[k] += red[k + s];
        __syncthreads();
    }
    if (k == 0) bias2[j] = bl[j] + red[0];
}

// ================= fused scatter (fixed-capacity buckets) + cvt + gb =================
__global__ __launch_bounds__(256)
void scatcvt_kernel(const float* __restrict__ x, const int* __restrict__ src,
                    const int* __restrict__ dst, const int* __restrict__ batch,
                    int* __restrict__ bcur, unsigned* __restrict__ staging,
                    f16* __restrict__ hf, int* __restrict__ gb) {
    if (blockIdx.x < NCNT) {
        __shared__ int h[NB];
        __shared__ int rbase[NB];
        for (int i = threadIdx.x; i < NB; i += 256) h[i] = 0;
        __syncthreads();
        int base = blockIdx.x * EPB;
#pragma unroll
        for (int it = 0; it < EPB / 256; ++it) {
            int e = base + it * 256 + threadIdx.x;
            if (e < NE) atomicAdd(&h[dst[e] >> 8], 1);
        }
        __syncthreads();
        for (int i = threadIdx.x; i < NB; i += 256) {
            rbase[i] = h[i] ? atomicAdd(&bcur[i], h[i]) : 0;
            h[i] = 0;
        }
        __syncthreads();
#pragma unroll
        for (int it = 0; it < EPB / 256; ++it) {
            int e = base + it * 256 + threadIdx.x;
            if (e < NE) {
                int d = dst[e];
                int k = d >> 8;
                int p = rbase[k] + atomicAdd(&h[k], 1);
                if (p < CAP)  // capacity guard (statistically impossible to trip)
                    staging[(size_t)k * CAP + p] = ((unsigned)d << 16) | (unsigned)src[e];
            }
        }
    } else {
        // ---- cvt block: fp32 -> fp16 row conversion + group-boundary table ----
        int t = (blockIdx.x - NCNT) * 256 + threadIdx.x;  // t < NN*16 exactly
        if (t < NN) {
            int b = batch[t];
            int bp = (t == 0) ? -1 : batch[t - 1];
            for (int g = bp + 1; g <= b; ++g) gb[g] = t;
            if (t == NN - 1)
                for (int g = b + 1; g <= NG; ++g) gb[g] = NN;
        }
        int n = t >> 4, q = t & 15;
        float4 v0 = ((const float4*)x)[n * 32 + q * 2];
        float4 v1 = ((const float4*)x)[n * 32 + q * 2 + 1];
        f16x8 o;
        o[0] = (f16)v0.x; o[1] = (f16)v0.y; o[2] = (f16)v0.z; o[3] = (f16)v0.w;
        o[4] = (f16)v1.x; o[5] = (f16)v1.y; o[6] = (f16)v1.z; o[7] = (f16)v1.w;
        *(f16x8*)(hf + (size_t)n * HD + q * 8) = o;
    }
}

// ===== per-bucket build (blocks 0..NB-1) + layer-0 weight prep (blocks NB..NB+127) =====
__global__ __launch_bounds__(256)
void buckbuild_kernel(const unsigned* __restrict__ staging, const int* __restrict__ bcur,
                      int* __restrict__ rowinfo, int* __restrict__ perm,
                      const float* __restrict__ Wl0, const float* __restrict__ Wr0,
                      const float* __restrict__ bl0, f16* __restrict__ Wh,
                      float* __restrict__ bias2) {
    __shared__ __align__(16) char sm[2048 + 2 * CAP];
    const int tid = threadIdx.x;
    if (blockIdx.x >= NB) {  // layer-0 weight prep rides along (no stats dependency)
        wprep_body(blockIdx.x - NB, tid, (float*)sm, nullptr, nullptr, nullptr,
                   Wl0, Wr0, bl0, Wh, bias2);
        return;
    }
    int* cnt = (int*)sm;
    int* pre = cnt + 256;
    unsigned short* lperm = (unsigned short*)(pre + 256);
    const int k = blockIdx.x;
    const int base = k * CAP;
    int size = bcur[k];
    if (size > CAP) size = CAP;
    cnt[tid] = 0;
    __syncthreads();
    for (int i = tid; i < size; i += 256)
        atomicAdd(&cnt[(int)(staging[base + i] >> 16) - k * 256], 1);
    __syncthreads();
    int v = cnt[tid];
    pre[tid] = v;
    __syncthreads();
    for (int off = 1; off < 256; off <<= 1) {
        int t2 = (tid >= off) ? pre[tid - off] : 0;
        __syncthreads();
        pre[tid] += t2;
        __syncthreads();
    }
    int excl = pre[tid] - v;
    int n = k * 256 + tid;
    if (n < NN) rowinfo[n] = excl | (v << 16);
    cnt[tid] = excl;  // reuse as scatter cursors
    __syncthreads();
    for (int i = tid; i < size; i += 256) {
        unsigned w = staging[base + i];
        int dl = (int)(w >> 16) - k * 256;
        int p = atomicAdd(&cnt[dl], 1);
        lperm[p] = (unsigned short)(w & 0xffffu);  // src < 65536 (NN=50000)
    }
    __syncthreads();
    for (int i = tid; i < size; i += 256) perm[base + i] = (int)lperm[i];
}

// ================= standalone weight prep for layers 1,2 (needs prev stats) =================
__global__ __launch_bounds__(256)
void wprep_kernel(const float* __restrict__ statsPrev, const float* __restrict__ gamP,
                  const float* __restrict__ betP, const float* __restrict__ Wl,
                  const float* __restrict__ Wr, const float* __restrict__ bl,
                  f16* __restrict__ Wh, float* __restrict__ bias2) {
    __shared__ float red[256];
    wprep_body(blockIdx.x, threadIdx.x, red, statsPrev, gamP, betP, Wl, Wr, bl, Wh, bias2);
}

// ===== fused16: channel-half phased gather -> M=16 MFMA GEMM; lastl pools in epilogue =====
// Phase hb gathers only channels hb*64..+63 (128B of each 256B row, 64B-aligned
// lines) -> per-phase device working set 6.4MB -> L2-resident -> fewer L3-serviced
// misses. Two edges/iteration via lane-octet parity, merged with one shfl_xor(8).
__global__ __launch_bounds__(256, 7)
void fused16_kernel(const f16* __restrict__ hin, const int* __restrict__ rowinfo,
                    const int* __restrict__ perm, const float* __restrict__ statsPrev,
                    const float* __restrict__ gamP, const float* __restrict__ betP,
                    const f16* __restrict__ Wh, const float* __restrict__ bias2,
                    f16* __restrict__ yout, float* __restrict__ statsN,
                    const int* __restrict__ batch, float* __restrict__ pooledR,
                    int lastl) {
    __shared__ __align__(16) f16 alds[16 * 72];   // 2304 B half-channel agg tile
    __shared__ __align__(16) f16 wls[128 * 68];   // 17408 B Wh K-chunk; aliased ls below
    __shared__ float st[256];                     // 1024 B channel sums/sqsums
    float* ls = (float*)wls;                      // [16][132] f32 epilogue stage
    const int tid = threadIdx.x;
    const int brow = blockIdx.x * 16;             // NN = 16*3125 exactly: no guards

    const int i16 = tid >> 4;       // node 0..15
    const int lane8 = tid & 7;      // channel octet within half
    const int oct = (tid >> 3) & 1; // edge parity
    const int n = brow + i16;
    const int ri = rowinfo[n];
    const int dg = ri >> 16;
    const int r0 = (n >> 8) * CAP + (ri & 0xffff);
    const int r1 = r0 + dg;

    const int lane = tid & 63, wave = tid >> 6;
    const int lm = lane & 15, kg = lane >> 4;
    const f16* hrow = hin + (size_t)(brow + lm) * HD;  // self-half K source
    f32x4 acc0 = (f32x4){0.f, 0.f, 0.f, 0.f};
    f32x4 acc1 = (f32x4){0.f, 0.f, 0.f, 0.f};

    // ---- phased gather + agg K-chunks (kc = hb) ----
#pragma unroll
    for (int hb = 0; hb < 2; ++hb) {
        {   // gather half hb: two edges per iteration (parity oct)
            const f16* hq = hin + hb * 64 + lane8 * 8;
            float s[8] = {0.f, 0.f, 0.f, 0.f, 0.f, 0.f, 0.f, 0.f};
            int e = r0;
            for (; e + 4 <= r1; e += 4) {
                int ia = perm[e + oct], ib = perm[e + 2 + oct];
                f16x8 va = *(const f16x8*)(hq + (size_t)ia * HD);
                f16x8 vb = *(const f16x8*)(hq + (size_t)ib * HD);
#pragma unroll
                for (int j = 0; j < 8; ++j) s[j] += (float)va[j] + (float)vb[j];
            }
            if (e + 2 <= r1) {
                int ia = perm[e + oct];
                f16x8 va = *(const f16x8*)(hq + (size_t)ia * HD);
#pragma unroll
                for (int j = 0; j < 8; ++j) s[j] += (float)va[j];
                e += 2;
            }
            if (e < r1 && oct == 0) {
                int ia = perm[e];
                f16x8 va = *(const f16x8*)(hq + (size_t)ia * HD);
#pragma unroll
                for (int j = 0; j < 8; ++j) s[j] += (float)va[j];
            }
            // merge edge-parity partials (lane k <-> k^8, within the node's 16 lanes)
#pragma unroll
            for (int j = 0; j < 8; ++j) s[j] += __shfl_xor(s[j], 8);
            if (dg > 0) {
                float rr = 1.0f / (float)dg;
#pragma unroll
                for (int j = 0; j < 8; ++j) s[j] *= rr;
            } else if (statsPrev) {
                // deg-0 sentinel: -sh/sc so the BN-folded GEMM contribution is 0
#pragma unroll
                for (int j = 0; j < 8; ++j) {
                    float sc, sh;
                    bn_affine(statsPrev, hb * 64 + lane8 * 8 + j, gamP, betP, &sc, &sh);
                    s[j] = (sc != 0.f) ? (-sh / sc) : 0.f;
                }
            }  // layer 0: sentinel 0, s[] already 0
            if (oct == 0) {
                f16x8 o;
#pragma unroll
                for (int j = 0; j < 8; ++j) o[j] = (f16)s[j];
                *(f16x8*)&alds[i16 * 72 + lane8 * 8] = o;
            }
        }
        // stage Wh[0..127][hb*64..+64) -> wls (independent LDS region, same phase)
#pragma unroll
        for (int it = 0; it < 4; ++it) {
            int slot = tid + it * 256;
            int r = slot >> 3, c = slot & 7;
            *(f16x8*)&wls[r * 68 + c * 8] =
                *(const f16x8*)(Wh + (size_t)r * 256 + hb * 64 + c * 8);
        }
        __syncthreads();
#pragma unroll
        for (int f = 0; f < 2; ++f) {
            f16x8 av = *(const f16x8*)&alds[lm * 72 + f * 32 + kg * 8];
            f16x8 b0 = *(const f16x8*)&wls[(wave * 32 + lm) * 68 + f * 32 + kg * 8];
            f16x8 b1 = *(const f16x8*)&wls[(wave * 32 + 16 + lm) * 68 + f * 32 + kg * 8];
            acc0 = __builtin_amdgcn_mfma_f32_16x16x32_f16(av, b0, acc0, 0, 0, 0);
            acc1 = __builtin_amdgcn_mfma_f32_16x16x32_f16(av, b1, acc1, 0, 0, 0);
        }
        __syncthreads();  // alds/wls reads done before next phase overwrites
    }

    // ---- self K-chunks (kc = 2,3): A from global contiguous rows ----
#pragma unroll
    for (int kc = 2; kc < 4; ++kc) {
#pragma unroll
        for (int it = 0; it < 4; ++it) {
            int slot = tid + it * 256;
            int r = slot >> 3, c = slot & 7;
            *(f16x8*)&wls[r * 68 + c * 8] =
                *(const f16x8*)(Wh + (size_t)r * 256 + kc * 64 + c * 8);
        }
        __syncthreads();
#pragma unroll
        for (int f = 0; f < 2; ++f) {
            f16x8 av = *(const f16x8*)(hrow + (kc - 2) * 64 + f * 32 + kg * 8);
            f16x8 b0 = *(const f16x8*)&wls[(wave * 32 + lm) * 68 + f * 32 + kg * 8];
            f16x8 b1 = *(const f16x8*)&wls[(wave * 32 + 16 + lm) * 68 + f * 32 + kg * 8];
            acc0 = __builtin_amdgcn_mfma_f32_16x16x32_f16(av, b0, acc0, 0, 0, 0);
            acc1 = __builtin_amdgcn_mfma_f32_16x16x32_f16(av, b1, acc1, 0, 0, 0);
        }
        __syncthreads();  // wls reads done before next stage (and before ls alias)
    }

    // ---- epilogue: bias+ReLU, stats, stage via ls ----
#pragma unroll
    for (int t = 0; t < 2; ++t) {
        int ch = (wave * 2 + t) * 16 + lm;  // output channel (C col = lane&15)
        float bs = bias2[ch];
        f32x4 A = t ? acc1 : acc0;
        float s = 0.f, sq = 0.f;
#pragma unroll
        for (int r = 0; r < 4; ++r) {       // C row = kg*4 + r
            float y = fmaxf(A[r] + bs, 0.f);
            ls[(kg * 4 + r) * 132 + ch] = y;
            s += y; sq += y * y;
        }
        s += __shfl_xor(s, 16); s += __shfl_xor(s, 32);
        sq += __shfl_xor(sq, 16); sq += __shfl_xor(sq, 32);
        if (kg == 0) { st[ch] = s; st[128 + ch] = sq; }  // single writer per slot
    }
    __syncthreads();
    atomicAdd(&statsN[(blockIdx.x & (NREP - 1)) * 256 + tid], st[tid]);
    if (!lastl) {
        int r = tid >> 4, oc = tid & 15;
        const float* p = &ls[r * 132 + oc * 8];
        f16x8 o;
#pragma unroll
        for (int j = 0; j < 8; ++j) o[j] = (f16)p[j];
        *(f16x8*)(yout + (size_t)(brow + r) * HD + oc * 8) = o;
    } else {
        // ---- pooling epilogue: output used only for group-sum -> never materialize ----
        float* pr = pooledR + (size_t)(blockIdx.x & 7) * NG * HD;
        int gmin = batch[brow], gmax = batch[brow + 15];
        if (gmin == gmax) {
            // st[c] == sum of this block's 16 rows (single group)
            if (tid < HD) atomicAdd(&pr[gmin * HD + tid], st[tid]);
        } else {
            // boundary (~2% of blocks): block spans exactly 2 groups (min group >> 16)
            int gg = tid >> 7, ch = tid & 127;
            int g = gmin + gg;
            if (g <= gmax) {
                float s = 0.f;
#pragma unroll
                for (int r = 0; r < 16; ++r)
                    if (batch[brow + r] == g) s += ls[r * 132 + ch];
                atomicAdd(&pr[g * HD + ch], s);
            }
        }
    }
}

// ---------------- head: layer-3 BN (replicated stats) + replica-summed pool + sigmoid ----
__global__ void head_kernel(const float* __restrict__ pooledR, const int* __restrict__ gb,
                            const float* __restrict__ stats3, const float* __restrict__ gam3,
                            const float* __restrict__ bet3, const float* __restrict__ fcw,
                            const float* __restrict__ fcb, float* __restrict__ out) {
    __shared__ float red[2];
    int g = blockIdx.x, c = threadIdx.x;  // 128 threads
    float sc, sh;
    bn_affine(stats3, c, gam3, bet3, &sc, &sh);
    float p = 0.f;
#pragma unroll
    for (int r = 0; r < 8; ++r) p += pooledR[(size_t)r * NG * HD + g * HD + c];
    float cnt = (float)(gb[g + 1] - gb[g]);
    float v = (p * sc + cnt * sh) * fcw[c];
#pragma unroll
    for (int o = 32; o > 0; o >>= 1) v += __shfl_xor(v, o);
    if ((c & 63) == 0) red[c >> 6] = v;
    __syncthreads();
    if (c == 0) {
        float s = red[0] + red[1] + fcb[0];
        out[g] = 1.0f / (1.0f + expf(-s));
    }
}

extern "C" void kernel_launch(void* const* d_in, const int* in_sizes, int n_in,
                              void* d_out, int out_size, void* d_ws, size_t ws_size,
                              hipStream_t stream) {
    const float* x     = (const float*)d_in[0];
    const int*   ei    = (const int*)d_in[1];
    const int*   src   = ei;
    const int*   dst   = ei + NE;
    const int*   batch = (const int*)d_in[3];
    const float* Wl    = (const float*)d_in[4];
    const float* bl    = (const float*)d_in[5];
    const float* Wr    = (const float*)d_in[6];
    const float* gamma = (const float*)d_in[7];
    const float* beta  = (const float*)d_in[8];
    const float* fcw   = (const float*)d_in[9];
    const float* fcb   = (const float*)d_in[10];
    float* out = (float*)d_out;

    f16* hf0  = (f16*)d_ws;                       // [NN][128] fp16 (x converted)
    f16* hfA  = hf0 + (size_t)NN * HD;
    f16* hfB  = hfA + (size_t)NN * HD;
    f16* Wh   = hfB + (size_t)NN * HD;            // [128][256] fp16
    float* bias2 = (float*)(Wh + 128 * 256);      // 128
    // ---- contiguous zero zone (single memset) ----
    float* zero0    = bias2 + HD;
    float* statsRaw = zero0;                      // 3 layers x NREP x 256
    float* pooledR  = statsRaw + 3 * NREP * 256;  // 8 replicas x NG x HD
    int* bcur  = (int*)(pooledR + 8 * NG * HD);   // NB relative cursors
    size_t zero_bytes = (3 * NREP * 256 + 8 * NG * HD) * sizeof(float) + NB * sizeof(int);
    // ---- rest ----
    int* rowinfo = bcur + NB;                     // NN
    int* gb      = rowinfo + NN;                  // NG+1
    int* perm    = gb + NG + 1;                   // NB*CAP (padded CSR)
    // staging ALIASES hfB: live window (scatcvt->buckbuild) ends before hfB's
    // first write (fused layer 1). R7/R10-proven aliasing.
    unsigned* staging = (unsigned*)hfB;           // NB*CAP (6.42MB < 12.8MB)

    hipMemsetAsync(zero0, 0, zero_bytes, stream);

    scatcvt_kernel<<<NCNT + GATHB, 256, 0, stream>>>(x, src, dst, batch, bcur,
                                                     staging, hf0, gb);
    buckbuild_kernel<<<NB + 128, 256, 0, stream>>>(staging, bcur, rowinfo, perm,
                                                   Wl, Wr, bl, Wh, bias2);

    const f16* hin = hf0;
    f16* houts[3] = {hfA, hfB, hfA};  // L2 output ignored (pooled in epilogue)
    for (int l = 0; l < NL; ++l) {
        const float* stP = (l == 0) ? nullptr : (statsRaw + (size_t)(l - 1) * NREP * 256);
        const float* gP  = gamma + (l == 0 ? 0 : (l - 1)) * HD;
        const float* bP  = beta + (l == 0 ? 0 : (l - 1)) * HD;
        if (l > 0)  // stream-ordered weight prep (layer l-1 stats complete)
            wprep_kernel<<<128, 256, 0, stream>>>(stP, gP, bP, Wl + (size_t)l * HD * HD,
                                                  Wr + (size_t)l * HD * HD, bl + l * HD,
                                                  Wh, bias2);
        fused16_kernel<<<FUSEB, 256, 0, stream>>>(
            hin, rowinfo, perm, stP, gP, bP, Wh, bias2,
            houts[l], statsRaw + (size_t)l * NREP * 256,
            batch, pooledR, (l == NL - 1) ? 1 : 0);
        hin = houts[l];
    }
    head_kernel<<<NG, 128, 0, stream>>>(pooledR, gb, statsRaw + 2 * NREP * 256,
                                        gamma + 2 * HD, beta + 2 * HD, fcw, fcb, out);
}

// Round 13
// 265.766 us; speedup vs baseline: 1.0029x; 1.0029x over previous
//
#include <hip/hip_runtime.h>
#include <math.h>

#define NN 50000
#define NE 800000
#define HD 128
#define NL 3
#define NG 64
#define BN_EPS 1e-5f
#define NB 196   // dst buckets of 256 nodes
#define EPB 4096 // edges per block in bucket scatter
#define NCNT ((NE + EPB - 1) / EPB)     // 196 scatter blocks
#define CAP 8192 // fixed bucket capacity (mean 4096 + 64 sigma)
#define NREP 32  // stats replicas (TCC same-address contention /32)
#define GATHB ((NN * 16) / 256)         // 3125 cvt blocks (exact)
#define FUSEB (NN / 16)                 // 3125 fused tiles (NN = 16*3125 exactly)

typedef _Float16 f16;
typedef __attribute__((ext_vector_type(8))) _Float16 f16x8;
typedef __attribute__((ext_vector_type(4))) float f32x4;

// BN affine from replicated raw sums
__device__ __forceinline__ void bn_affine(const float* __restrict__ sR, int c,
                                          const float* __restrict__ gam,
                                          const float* __restrict__ bet,
                                          float* sc, float* sh) {
    float s0 = 0.f, s1 = 0.f;
#pragma unroll 8
    for (int r = 0; r < NREP; ++r) {
        s0 += sR[r * 256 + c];
        s1 += sR[r * 256 + 128 + c];
    }
    float invN = 1.0f / (float)NN;
    float mu = s0 * invN;
    float var = s1 * invN - mu * mu;
    var = var < 0.f ? 0.f : var;
    float s = rsqrtf(var + BN_EPS) * gam[c];
    *sc = s;
    *sh = bet[c] - mu * s;
}

// weight prep body: BN-folded Wh (fp16) + folded bias2. One block per output ch j.
__device__ __forceinline__ void wprep_body(int j, int k, float* red,
                                           const float* __restrict__ statsPrev,
                                           const float* __restrict__ gamP,
                                           const float* __restrict__ betP,
                                           const float* __restrict__ Wl,
                                           const float* __restrict__ Wr,
                                           const float* __restrict__ bl,
                                           f16* __restrict__ Wh,
                                           float* __restrict__ bias2) {
    float scp = 1.0f, shp = 0.0f;
    if (statsPrev) bn_affine(statsPrev, k & 127, gamP, betP, &scp, &shp);
    float w = (k < HD) ? Wl[j * HD + k] : Wr[j * HD + (k - HD)];
    Wh[j * 256 + k] = (f16)(w * scp);
    red[k] = shp * w;
    __syncthreads();
    for (int s = 128; s > 0; s >>= 1) {
        if (k < s) red[k] += red[k + s];
        __syncthreads();
    }
    if (k == 0) bias2[j] = bl[j] + red[0];
}

// ================= fused scatter (fixed-capacity buckets) + cvt + gb =================
__global__ __launch_bounds__(256)
void scatcvt_kernel(const float* __restrict__ x, const int* __restrict__ src,
                    const int* __restrict__ dst, const int* __restrict__ batch,
                    int* __restrict__ bcur, unsigned* __restrict__ staging,
                    f16* __restrict__ hf, int* __restrict__ gb) {
    if (blockIdx.x < NCNT) {
        __shared__ int h[NB];
        __shared__ int rbase[NB];
        for (int i = threadIdx.x; i < NB; i += 256) h[i] = 0;
        __syncthreads();
        int base = blockIdx.x * EPB;
#pragma unroll
        for (int it = 0; it < EPB / 256; ++it) {
            int e = base + it * 256 + threadIdx.x;
            if (e < NE) atomicAdd(&h[dst[e] >> 8], 1);
        }
        __syncthreads();
        for (int i = threadIdx.x; i < NB; i += 256) {
            rbase[i] = h[i] ? atomicAdd(&bcur[i], h[i]) : 0;
            h[i] = 0;
        }
        __syncthreads();
#pragma unroll
        for (int it = 0; it < EPB / 256; ++it) {
            int e = base + it * 256 + threadIdx.x;
            if (e < NE) {
                int d = dst[e];
                int k = d >> 8;
                int p = rbase[k] + atomicAdd(&h[k], 1);
                if (p < CAP)  // capacity guard (statistically impossible to trip)
                    staging[(size_t)k * CAP + p] = ((unsigned)d << 16) | (unsigned)src[e];
            }
        }
    } else {
        // ---- cvt block: fp32 -> fp16 row conversion + group-boundary table ----
        int t = (blockIdx.x - NCNT) * 256 + threadIdx.x;  // t < NN*16 exactly
        if (t < NN) {
            int b = batch[t];
            int bp = (t == 0) ? -1 : batch[t - 1];
            for (int g = bp + 1; g <= b; ++g) gb[g] = t;
            if (t == NN - 1)
                for (int g = b + 1; g <= NG; ++g) gb[g] = NN;
        }
        int n = t >> 4, q = t & 15;
        float4 v0 = ((const float4*)x)[n * 32 + q * 2];
        float4 v1 = ((const float4*)x)[n * 32 + q * 2 + 1];
        f16x8 o;
        o[0] = (f16)v0.x; o[1] = (f16)v0.y; o[2] = (f16)v0.z; o[3] = (f16)v0.w;
        o[4] = (f16)v1.x; o[5] = (f16)v1.y; o[6] = (f16)v1.z; o[7] = (f16)v1.w;
        *(f16x8*)(hf + (size_t)n * HD + q * 8) = o;
    }
}

// ===== per-bucket build (blocks 0..NB-1) + layer-0 weight prep (blocks NB..NB+127) =====
__global__ __launch_bounds__(256)
void buckbuild_kernel(const unsigned* __restrict__ staging, const int* __restrict__ bcur,
                      int* __restrict__ rowinfo, int* __restrict__ perm,
                      const float* __restrict__ Wl0, const float* __restrict__ Wr0,
                      const float* __restrict__ bl0, f16* __restrict__ Wh,
                      float* __restrict__ bias2) {
    __shared__ __align__(16) char sm[2048 + 2 * CAP];
    const int tid = threadIdx.x;
    if (blockIdx.x >= NB) {  // layer-0 weight prep rides along (no stats dependency)
        wprep_body(blockIdx.x - NB, tid, (float*)sm, nullptr, nullptr, nullptr,
                   Wl0, Wr0, bl0, Wh, bias2);
        return;
    }
    int* cnt = (int*)sm;
    int* pre = cnt + 256;
    unsigned short* lperm = (unsigned short*)(pre + 256);
    const int k = blockIdx.x;
    const int base = k * CAP;
    int size = bcur[k];
    if (size > CAP) size = CAP;
    cnt[tid] = 0;
    __syncthreads();
    for (int i = tid; i < size; i += 256)
        atomicAdd(&cnt[(int)(staging[base + i] >> 16) - k * 256], 1);
    __syncthreads();
    int v = cnt[tid];
    pre[tid] = v;
    __syncthreads();
    for (int off = 1; off < 256; off <<= 1) {
        int t2 = (tid >= off) ? pre[tid - off] : 0;
        __syncthreads();
        pre[tid] += t2;
        __syncthreads();
    }
    int excl = pre[tid] - v;
    int n = k * 256 + tid;
    if (n < NN) rowinfo[n] = excl | (v << 16);
    cnt[tid] = excl;  // reuse as scatter cursors
    __syncthreads();
    for (int i = tid; i < size; i += 256) {
        unsigned w = staging[base + i];
        int dl = (int)(w >> 16) - k * 256;
        int p = atomicAdd(&cnt[dl], 1);
        lperm[p] = (unsigned short)(w & 0xffffu);  // src < 65536 (NN=50000)
    }
    __syncthreads();
    for (int i = tid; i < size; i += 256) perm[base + i] = (int)lperm[i];
}

// ================= standalone weight prep for layers 1,2 (needs prev stats) =================
__global__ __launch_bounds__(256)
void wprep_kernel(const float* __restrict__ statsPrev, const float* __restrict__ gamP,
                  const float* __restrict__ betP, const float* __restrict__ Wl,
                  const float* __restrict__ Wr, const float* __restrict__ bl,
                  f16* __restrict__ Wh, float* __restrict__ bias2) {
    __shared__ float red[256];
    wprep_body(blockIdx.x, threadIdx.x, red, statsPrev, gamP, betP, Wl, Wr, bl, Wh, bias2);
}

// ===== fused16: gather 16 nodes -> M=16 MFMA GEMM; lastl pools in epilogue =====
// R11 structure, LDS-slimmed for 8 blocks/CU (32/32 waves): Wh staged in eight
// 32-wide K-chunks (wls 9216B) and st aliased into dead alds region. Total LDS
// 13568B. Gather (the long pole) gets +14% resident waves for miss overlap.
__global__ __launch_bounds__(256, 8)
void fused16_kernel(const f16* __restrict__ hin, const int* __restrict__ rowinfo,
                    const int* __restrict__ perm, const float* __restrict__ statsPrev,
                    const float* __restrict__ gamP, const float* __restrict__ betP,
                    const f16* __restrict__ Wh, const float* __restrict__ bias2,
                    f16* __restrict__ yout, float* __restrict__ statsN,
                    const int* __restrict__ batch, float* __restrict__ pooledR,
                    int lastl) {
    __shared__ __align__(16) f16 alds[16 * 136];  // 4352 B agg tile; st aliases after use
    __shared__ __align__(16) f16 wls[128 * 36];   // 9216 B Wh 32-wide K-chunk; ls alias
    float* ls = (float*)wls;                      // [16][132] f32 epilogue stage (8448B)
    float* st = (float*)alds;                     // [256] stats (alds dead by epilogue)
    const int tid = threadIdx.x;
    const int brow = blockIdx.x * 16;             // NN = 16*3125 exactly: no guards

    // ---- gather phase: node i = tid>>4, channel octet q = tid&15 (R10/R11-proven) ----
    {
        int i = tid >> 4, q = tid & 15;
        int n = brow + i;
        int ri = rowinfo[n];
        int dg = ri >> 16;
        int r0 = (n >> 8) * CAP + (ri & 0xffff);
        int r1 = r0 + dg;
        const f16* hq = hin + q * 8;
        float s[8] = {0.f, 0.f, 0.f, 0.f, 0.f, 0.f, 0.f, 0.f};
        int e = r0;
        for (; e + 4 <= r1; e += 4) {
            int i0 = perm[e], i1 = perm[e + 1], i2 = perm[e + 2], i3 = perm[e + 3];
            f16x8 v0 = *(const f16x8*)(hq + (size_t)i0 * HD);
            f16x8 v1 = *(const f16x8*)(hq + (size_t)i1 * HD);
            f16x8 v2 = *(const f16x8*)(hq + (size_t)i2 * HD);
            f16x8 v3 = *(const f16x8*)(hq + (size_t)i3 * HD);
#pragma unroll
            for (int j = 0; j < 8; ++j)
                s[j] += ((float)v0[j] + (float)v1[j]) + ((float)v2[j] + (float)v3[j]);
        }
        if (e + 2 <= r1) {
            int i0 = perm[e], i1 = perm[e + 1];
            f16x8 v0 = *(const f16x8*)(hq + (size_t)i0 * HD);
            f16x8 v1 = *(const f16x8*)(hq + (size_t)i1 * HD);
#pragma unroll
            for (int j = 0; j < 8; ++j) s[j] += (float)v0[j] + (float)v1[j];
            e += 2;
        }
        if (e < r1) {
            int i0 = perm[e];
            f16x8 v0 = *(const f16x8*)(hq + (size_t)i0 * HD);
#pragma unroll
            for (int j = 0; j < 8; ++j) s[j] += (float)v0[j];
        }
        if (dg > 0) {
            float rr = 1.0f / (float)dg;
#pragma unroll
            for (int j = 0; j < 8; ++j) s[j] *= rr;
        } else if (statsPrev) {
            // deg-0 sentinel: -sh/sc so the BN-folded GEMM contribution is exactly 0
#pragma unroll
            for (int j = 0; j < 8; ++j) {
                float sc, sh;
                bn_affine(statsPrev, q * 8 + j, gamP, betP, &sc, &sh);
                s[j] = (sc != 0.f) ? (-sh / sc) : 0.f;
            }
        }  // layer 0: sentinel is 0 (identity affine), s[] already 0
        f16x8 o;
#pragma unroll
        for (int j = 0; j < 8; ++j) o[j] = (f16)s[j];
        *(f16x8*)&alds[i * 136 + q * 8] = o;
    }

    const int lane = tid & 63, wave = tid >> 6;
    const int lm = lane & 15, kg = lane >> 4;
    const f16* hrow = hin + (size_t)(brow + lm) * HD;  // self-half K source
    f32x4 acc0 = (f32x4){0.f, 0.f, 0.f, 0.f};
    f32x4 acc1 = (f32x4){0.f, 0.f, 0.f, 0.f};
    __syncthreads();  // alds ready

    // ---- GEMM: M=16, N=128, K=256 in eight 32-wide K-chunks ----
#pragma unroll
    for (int kc = 0; kc < 8; ++kc) {
        // stage Wh[0..127][kc*32..+32) -> wls[128][36]
#pragma unroll
        for (int it = 0; it < 2; ++it) {
            int slot = tid + it * 256;       // 512 slots
            int r = slot >> 2, c = slot & 3;
            *(f16x8*)&wls[r * 36 + c * 8] =
                *(const f16x8*)(Wh + (size_t)r * 256 + kc * 32 + c * 8);
        }
        __syncthreads();
        f16x8 av;
        if (kc < 4)  // agg half from LDS
            av = *(const f16x8*)&alds[lm * 136 + kc * 32 + kg * 8];
        else         // self half from global (L2-warm contiguous rows)
            av = *(const f16x8*)(hrow + (kc - 4) * 32 + kg * 8);
        f16x8 b0 = *(const f16x8*)&wls[(wave * 32 + lm) * 36 + kg * 8];
        f16x8 b1 = *(const f16x8*)&wls[(wave * 32 + 16 + lm) * 36 + kg * 8];
        acc0 = __builtin_amdgcn_mfma_f32_16x16x32_f16(av, b0, acc0, 0, 0, 0);
        acc1 = __builtin_amdgcn_mfma_f32_16x16x32_f16(av, b1, acc1, 0, 0, 0);
        __syncthreads();  // wls (and alds for kc<4) reads done before next stage
    }

    // ---- epilogue: bias+ReLU, stats, stage via ls (st aliases dead alds) ----
#pragma unroll
    for (int t = 0; t < 2; ++t) {
        int ch = (wave * 2 + t) * 16 + lm;  // output channel (C col = lane&15)
        float bs = bias2[ch];
        f32x4 A = t ? acc1 : acc0;
        float s = 0.f, sq = 0.f;
#pragma unroll
        for (int r = 0; r < 4; ++r) {       // C row = kg*4 + r
            float y = fmaxf(A[r] + bs, 0.f);
            ls[(kg * 4 + r) * 132 + ch] = y;
            s += y; sq += y * y;
        }
        s += __shfl_xor(s, 16); s += __shfl_xor(s, 32);
        sq += __shfl_xor(sq, 16); sq += __shfl_xor(sq, 32);
        if (kg == 0) { st[ch] = s; st[128 + ch] = sq; }  // single writer per slot
    }
    __syncthreads();
    atomicAdd(&statsN[(blockIdx.x & (NREP - 1)) * 256 + tid], st[tid]);
    if (!lastl) {
        int r = tid >> 4, oc = tid & 15;
        const float* p = &ls[r * 132 + oc * 8];
        f16x8 o;
#pragma unroll
        for (int j = 0; j < 8; ++j) o[j] = (f16)p[j];
        *(f16x8*)(yout + (size_t)(brow + r) * HD + oc * 8) = o;
    } else {
        // ---- pooling epilogue: output used only for group-sum -> never materialize ----
        float* pr = pooledR + (size_t)(blockIdx.x & 7) * NG * HD;
        int gmin = batch[brow], gmax = batch[brow + 15];
        if (gmin == gmax) {
            // st[c] == sum of this block's 16 rows (single group)
            if (tid < HD) atomicAdd(&pr[gmin * HD + tid], st[tid]);
        } else {
            // boundary (~2% of blocks): block spans exactly 2 groups (min group >> 16)
            int gg = tid >> 7, ch = tid & 127;
            int g = gmin + gg;
            if (g <= gmax) {
                float s = 0.f;
#pragma unroll
                for (int r = 0; r < 16; ++r)
                    if (batch[brow + r] == g) s += ls[r * 132 + ch];
                atomicAdd(&pr[g * HD + ch], s);
            }
        }
    }
}

// ---------------- head: layer-3 BN (replicated stats) + replica-summed pool + sigmoid ----
__global__ void head_kernel(const float* __restrict__ pooledR, const int* __restrict__ gb,
                            const float* __restrict__ stats3, const float* __restrict__ gam3,
                            const float* __restrict__ bet3, const float* __restrict__ fcw,
                            const float* __restrict__ fcb, float* __restrict__ out) {
    __shared__ float red[2];
    int g = blockIdx.x, c = threadIdx.x;  // 128 threads
    float sc, sh;
    bn_affine(stats3, c, gam3, bet3, &sc, &sh);
    float p = 0.f;
#pragma unroll
    for (int r = 0; r < 8; ++r) p += pooledR[(size_t)r * NG * HD + g * HD + c];
    float cnt = (float)(gb[g + 1] - gb[g]);
    float v = (p * sc + cnt * sh) * fcw[c];
#pragma unroll
    for (int o = 32; o > 0; o >>= 1) v += __shfl_xor(v, o);
    if ((c & 63) == 0) red[c >> 6] = v;
    __syncthreads();
    if (c == 0) {
        float s = red[0] + red[1] + fcb[0];
        out[g] = 1.0f / (1.0f + expf(-s));
    }
}

extern "C" void kernel_launch(void* const* d_in, const int* in_sizes, int n_in,
                              void* d_out, int out_size, void* d_ws, size_t ws_size,
                              hipStream_t stream) {
    const float* x     = (const float*)d_in[0];
    const int*   ei    = (const int*)d_in[1];
    const int*   src   = ei;
    const int*   dst   = ei + NE;
    const int*   batch = (const int*)d_in[3];
    const float* Wl    = (const float*)d_in[4];
    const float* bl    = (const float*)d_in[5];
    const float* Wr    = (const float*)d_in[6];
    const float* gamma = (const float*)d_in[7];
    const float* beta  = (const float*)d_in[8];
    const float* fcw   = (const float*)d_in[9];
    const float* fcb   = (const float*)d_in[10];
    float* out = (float*)d_out;

    f16* hf0  = (f16*)d_ws;                       // [NN][128] fp16 (x converted)
    f16* hfA  = hf0 + (size_t)NN * HD;
    f16* hfB  = hfA + (size_t)NN * HD;
    f16* Wh   = hfB + (size_t)NN * HD;            // [128][256] fp16
    float* bias2 = (float*)(Wh + 128 * 256);      // 128
    // ---- contiguous zero zone (single memset) ----
    float* zero0    = bias2 + HD;
    float* statsRaw = zero0;                      // 3 layers x NREP x 256
    float* pooledR  = statsRaw + 3 * NREP * 256;  // 8 replicas x NG x HD
    int* bcur  = (int*)(pooledR + 8 * NG * HD);   // NB relative cursors
    size_t zero_bytes = (3 * NREP * 256 + 8 * NG * HD) * sizeof(float) + NB * sizeof(int);
    // ---- rest ----
    int* rowinfo = bcur + NB;                     // NN
    int* gb      = rowinfo + NN;                  // NG+1
    int* perm    = gb + NG + 1;                   // NB*CAP (padded CSR)
    // staging ALIASES hfB: live window (scatcvt->buckbuild) ends before hfB's
    // first write (fused layer 1). R7/R10/R11-proven aliasing.
    unsigned* staging = (unsigned*)hfB;           // NB*CAP (6.42MB < 12.8MB)

    hipMemsetAsync(zero0, 0, zero_bytes, stream);

    scatcvt_kernel<<<NCNT + GATHB, 256, 0, stream>>>(x, src, dst, batch, bcur,
                                                     staging, hf0, gb);
    buckbuild_kernel<<<NB + 128, 256, 0, stream>>>(staging, bcur, rowinfo, perm,
                                                   Wl, Wr, bl, Wh, bias2);

    const f16* hin = hf0;
    f16* houts[3] = {hfA, hfB, hfA};  // L2 output ignored (pooled in epilogue)
    for (int l = 0; l < NL; ++l) {
        const float* stP = (l == 0) ? nullptr : (statsRaw + (size_t)(l - 1) * NREP * 256);
        const float* gP  = gamma + (l == 0 ? 0 : (l - 1)) * HD;
        const float* bP  = beta + (l == 0 ? 0 : (l - 1)) * HD;
        if (l > 0)  // stream-ordered weight prep (layer l-1 stats complete)
            wprep_kernel<<<128, 256, 0, stream>>>(stP, gP, bP, Wl + (size_t)l * HD * HD,
                                                  Wr + (size_t)l * HD * HD, bl + l * HD,
                                                  Wh, bias2);
        fused16_kernel<<<FUSEB, 256, 0, stream>>>(
            hin, rowinfo, perm, stP, gP, bP, Wh, bias2,
            houts[l], statsRaw + (size_t)l * NREP * 256,
            batch, pooledR, (l == NL - 1) ? 1 : 0);
        hin = houts[l];
    }
    head_kernel<<<NG, 128, 0, stream>>>(pooledR, gb, statsRaw + 2 * NREP * 256,
                                        gamma + 2 * HD, beta + 2 * HD, fcw, fcb, out);
}